// Round 1
// baseline (578.390 us; speedup 1.0000x reference)
//
#include <hip/hip_runtime.h>

// ---------------------------------------------------------------------------
// SynthesisLayer (StyleGAN2 modulated conv) on MI355X.
// Decomposition:
//   s[b,i]   = w[b,:] @ sw[i,:]^T * SS + sb[i]
//   csq[o,i] = CS^2 * sum_t cw[o,i,t]^2
//   sig[b,o] = rsqrt( sum_i s^2[b,i]*csq[o,i] + eps )
//   x'[b,h,w,i] = bf16( x[b,i,h,w] * s[b,i] )            (transpose + modulate)
//   cwt[ic,tap,g,o,j] = bf16( cw[o, ic*32+g*8+j, tap]*CS ) (MFMA-staging layout)
//   y[b,o,h,w] = sig[b,o] * conv(x', cwt) + nw[o]*noise[b,h,w] + bias[o]; leaky 0.2
// ---------------------------------------------------------------------------

typedef __attribute__((ext_vector_type(8))) short short8;    // 8 x bf16 (4 VGPR)
typedef __attribute__((ext_vector_type(4))) float f32x4;     // mfma acc

#define STYLE_SCALE 0.044194173824159216f   /* 1/sqrt(512)  */
#define CONV_SCALE  0.014731391274719742f   /* 1/sqrt(4608) */
#define CS2         (1.0f/4608.0f)

static __device__ __forceinline__ unsigned short f2bf(float x) {
    union { float f; unsigned int u; } a; a.f = x;
    unsigned int r = a.u + 0x7fffu + ((a.u >> 16) & 1u);    // round-nearest-even
    return (unsigned short)(r >> 16);
}

static __device__ __forceinline__ void gl_lds16(const void* g, void* l) {
    __builtin_amdgcn_global_load_lds(
        (const __attribute__((address_space(1))) unsigned int*)g,
        (__attribute__((address_space(3))) unsigned int*)l, 16, 0, 0);
}

// ---------------- kernel 1: style linear  s[16,512] -----------------------
__global__ void k_style(const float* __restrict__ w, const float* __restrict__ sw,
                        const float* __restrict__ sb, float* __restrict__ s) {
    int b = blockIdx.x, t = threadIdx.x;
    __shared__ float wl[512];
    wl[t]       = w[b*512 + t];
    wl[t + 256] = w[b*512 + t + 256];
    __syncthreads();
    for (int j = t; j < 512; j += 256) {
        const float4* row = (const float4*)(sw + j*512);
        float acc = 0.f;
#pragma unroll 4
        for (int k = 0; k < 128; ++k) {
            float4 v = row[k];
            acc += v.x*wl[4*k] + v.y*wl[4*k+1] + v.z*wl[4*k+2] + v.w*wl[4*k+3];
        }
        s[b*512 + j] = acc * STYLE_SCALE + sb[j];
    }
}

// ---------------- kernel 2: csq[o,i] = CS^2 * sum_t cw^2 ------------------
__global__ void k_csq(const float* __restrict__ cw, float* __restrict__ csq) {
    int o = blockIdx.x, t = threadIdx.x;
    for (int i = t; i < 512; i += 256) {
        const float* p = cw + (size_t)(o*512 + i)*9;
        float a = 0.f;
#pragma unroll
        for (int k = 0; k < 9; ++k) { float v = p[k]; a += v*v; }
        csq[o*512 + i] = a * CS2;
    }
}

// ---------------- kernel 3: sigma[b,o] ------------------------------------
__global__ void k_sigma(const float* __restrict__ s, const float* __restrict__ csq,
                        float* __restrict__ sig) {
    int b = blockIdx.x, t = threadIdx.x;
    __shared__ float s2[512];
    float v0 = s[b*512 + t], v1 = s[b*512 + t + 256];
    s2[t] = v0*v0; s2[t+256] = v1*v1;
    __syncthreads();
    for (int o = t; o < 512; o += 256) {
        const float4* row = (const float4*)(csq + o*512);
        float acc = 0.f;
#pragma unroll 4
        for (int k = 0; k < 128; ++k) {
            float4 c = row[k];
            acc += c.x*s2[4*k] + c.y*s2[4*k+1] + c.z*s2[4*k+2] + c.w*s2[4*k+3];
        }
        sig[b*512 + o] = 1.0f / sqrtf(acc + 1e-6f);
    }
}

// ------- kernel 4: x' transpose+modulate -> xt[b][h*64+w][c] bf16 ---------
__global__ void k_xt(const float* __restrict__ x, const float* __restrict__ s,
                     unsigned short* __restrict__ xt) {
    int h = blockIdx.x, b = blockIdx.y, t = threadIdx.x;
    __shared__ float tile[64][65];
    for (int c0 = 0; c0 < 512; c0 += 64) {
        for (int it = 0; it < 16; ++it) {
            int idx = t + it*256, c = idx >> 6, wq = idx & 63;
            tile[c][wq] = x[((size_t)(b*512 + c0 + c)*64 + h)*64 + wq];
        }
        __syncthreads();
        for (int it = 0; it < 4; ++it) {
            int idx = t + it*256;            // 1024 quads: [w][c/4]
            int wq = idx >> 4, c = (idx & 15) * 4;
            float s0 = s[b*512 + c0 + c],     s1 = s[b*512 + c0 + c + 1];
            float s2v = s[b*512 + c0 + c + 2], s3 = s[b*512 + c0 + c + 3];
            ushort4 pk;
            pk.x = f2bf(tile[c][wq]   * s0);
            pk.y = f2bf(tile[c+1][wq] * s1);
            pk.z = f2bf(tile[c+2][wq] * s2v);
            pk.w = f2bf(tile[c+3][wq] * s3);
            *(ushort4*)(xt + ((size_t)(b*4096 + h*64 + wq)*512 + c0 + c)) = pk;
        }
        __syncthreads();
    }
}

// ------- kernel 5: weight pack -> cwt[ic][tap][g][o][j] bf16 --------------
__global__ void k_cwt(const float* __restrict__ cw, unsigned short* __restrict__ cwt) {
    int p = blockIdx.x;                      // (ic*9+tap)*4+g, 0..575
    int g = p & 3, pt = p >> 2;
    int tap = pt % 9, ic = pt / 9;
    int i0 = ic*32 + g*8;
    int t = threadIdx.x;
    for (int o = t; o < 512; o += 256) {
        union { unsigned short us[8]; uint4 q; } u;
#pragma unroll
        for (int j = 0; j < 8; ++j)
            u.us[j] = f2bf(cw[((size_t)o*512 + i0 + j)*9 + tap] * CONV_SCALE);
        *(uint4*)(cwt + ((size_t)p*512 + o)*8) = u.q;
    }
}

// ---------------- kernel 6: implicit-GEMM MFMA conv -----------------------
// block: 64 o  x 256 px (4 rows), 4 waves; wave = 64 o x 64 px (one row)
// LDS: xs[6 rows][66 cols][32 ch] bf16 (ch-group XOR-swizzled by col&3)
//      wsm[9 tap][4 g][64 o][8 j] bf16
__global__ __launch_bounds__(256, 2)
void k_conv(const unsigned short* __restrict__ xt, const unsigned short* __restrict__ cwt,
            const float* __restrict__ sig, const float* __restrict__ nw,
            const float* __restrict__ bias, const float* __restrict__ noise,
            float* __restrict__ out) {
    __shared__ short xs_s[6*66*32];          // 25344 B
    __shared__ short wsm_s[9*4*64*8];        // 36864 B

    const int tid  = threadIdx.x;
    const int lane = tid & 63;
    const int wave = tid >> 6;               // = wave's row within the 4-row tile
    const int quad = lane >> 4;
    const int l15  = lane & 15;

    const int b     = blockIdx.y;
    const int oblk  = blockIdx.x & 7;
    const int pxblk = blockIdx.x >> 3;
    const int o0 = oblk * 64, h0 = pxblk * 4;

    // zero xs once: halo cols + out-of-image rows stay 0 forever
    for (int i = tid; i < 6*66*32/2; i += 256) ((unsigned int*)xs_s)[i] = 0u;
    __syncthreads();

    f32x4 acc[4][4];
#pragma unroll
    for (int mt = 0; mt < 4; ++mt)
#pragma unroll
        for (int nt = 0; nt < 4; ++nt) acc[mt][nt] = (f32x4){0.f, 0.f, 0.f, 0.f};

    for (int ic = 0; ic < 16; ++ic) {
        // ---- stage: 36 weight pairs + 24 x-row chunks, all global_load_lds x16B
        for (int q = wave; q < 60; q += 4) {
            if (q < 36) {
                const unsigned short* src = cwt + ((size_t)(ic*36 + q)*512 + o0 + lane)*8;
                gl_lds16(src, wsm_s + q*512);
            } else {
                int xq = q - 36;
                int r = xq >> 2, p0 = (xq & 3) << 4;
                int gr = h0 - 1 + r;
                if (gr >= 0 && gr < 64) {
                    int p  = p0 + (lane >> 2);                    // pixel (w coord)
                    int cg = (lane & 3) ^ ((lane >> 2) & 3);      // swizzled ch-group
                    const unsigned short* src =
                        xt + ((size_t)(b*4096 + gr*64 + p)*512 + ic*32 + cg*8);
                    gl_lds16(src, xs_s + (r*66 + 1 + p0)*32);
                }
            }
        }
        __syncthreads();

        // ---- compute: 9 taps x (4 A + 4 B ds_read_b128) x 16 mfma
#pragma unroll
        for (int tap = 0; tap < 9; ++tap) {
            const int dy = tap / 3, dx = tap % 3;
            short8 af[4], bfr[4];
            const short8* wp = (const short8*)wsm_s;
            const short8* xp = (const short8*)xs_s;
#pragma unroll
            for (int mt = 0; mt < 4; ++mt)
                af[mt] = wp[(tap*4 + quad)*64 + mt*16 + l15];
#pragma unroll
            for (int nt = 0; nt < 4; ++nt) {
                int wc   = nt*16 + l15 + dx - 1;                  // global col, -1..64
                int col  = wc + 1;
                int slot = quad ^ (wc & 3);
                bfr[nt] = xp[((wave + dy)*66 + col)*4 + slot];
            }
#pragma unroll
            for (int mt = 0; mt < 4; ++mt)
#pragma unroll
                for (int nt = 0; nt < 4; ++nt)
                    acc[mt][nt] = __builtin_amdgcn_mfma_f32_16x16x32_bf16(
                        af[mt], bfr[nt], acc[mt][nt], 0, 0, 0);
        }
        __syncthreads();
    }

    // ---- epilogue: sigma scale + noise + bias + leaky relu ----
    const int h = h0 + wave;
    float nz[4];
#pragma unroll
    for (int nt = 0; nt < 4; ++nt) nz[nt] = noise[b*4096 + h*64 + nt*16 + l15];
#pragma unroll
    for (int mt = 0; mt < 4; ++mt) {
#pragma unroll
        for (int r = 0; r < 4; ++r) {
            int o = o0 + mt*16 + quad*4 + r;
            float sg = sig[b*512 + o];
            float nwv = nw[o], bv = bias[o];
#pragma unroll
            for (int nt = 0; nt < 4; ++nt) {
                float v = acc[mt][nt][r] * sg + nwv * nz[nt] + bv;
                v = (v >= 0.f) ? v : 0.2f * v;
                out[((size_t)(b*512 + o)*4096) + h*64 + nt*16 + l15] = v;
            }
        }
    }
}

// ---------------------------------------------------------------------------
extern "C" void kernel_launch(void* const* d_in, const int* in_sizes, int n_in,
                              void* d_out, int out_size, void* d_ws, size_t ws_size,
                              hipStream_t stream) {
    const float* x     = (const float*)d_in[0];
    const float* w     = (const float*)d_in[1];
    const float* sw    = (const float*)d_in[2];
    const float* sb    = (const float*)d_in[3];
    const float* cw    = (const float*)d_in[4];
    const float* nw    = (const float*)d_in[5];
    const float* bias  = (const float*)d_in[6];
    const float* noise = (const float*)d_in[7];
    float* out = (float*)d_out;

    char* ws = (char*)d_ws;
    unsigned short* xt  = (unsigned short*)(ws + 0);          // 67,108,864 B
    unsigned short* cwt = (unsigned short*)(ws + 67108864);   //  4,718,592 B
    float* s   = (float*)(ws + 71827456);                     //     32,768 B
    float* sig = (float*)(ws + 71860224);                     //     32,768 B
    float* csq = (float*)(ws + 71892992);                     //  1,048,576 B

    k_style<<<16, 256, 0, stream>>>(w, sw, sb, s);
    k_csq  <<<512, 256, 0, stream>>>(cw, csq);
    k_sigma<<<16, 256, 0, stream>>>(s, csq, sig);
    k_xt   <<<dim3(64, 16), 256, 0, stream>>>(x, s, xt);
    k_cwt  <<<576, 256, 0, stream>>>(cw, cwt);
    k_conv <<<dim3(128, 16), 256, 0, stream>>>(xt, cwt, sig, nw, bias, noise, out);
}

// Round 2
// 491.789 us; speedup vs baseline: 1.1761x; 1.1761x over previous
//
#include <hip/hip_runtime.h>

// ---------------------------------------------------------------------------
// SynthesisLayer (StyleGAN2 modulated conv) on MI355X.
//   s[b,i]   = w[b,:] @ sw[i,:]^T * SS + sb[i]
//   csq[o,i] = CS^2 * sum_t cw[o,i,t]^2
//   sig[b,o] = rsqrt( sum_i s^2[b,i]*csq[o,i] + eps )
//   x'[b,h,w,i] = bf16( x[b,i,h,w] * s[b,i] )
//   cwt[ic,tap,g,o,j] = bf16( cw[o, ic*32+g*8+j, tap]*CS )
//   y = sig * conv(x', cwt) + nw*noise + bias; leaky 0.2
// ---------------------------------------------------------------------------

typedef __attribute__((ext_vector_type(8))) short short8;    // 8 x bf16
typedef __attribute__((ext_vector_type(4))) float f32x4;     // mfma acc

#define STYLE_SCALE 0.044194173824159216f   /* 1/sqrt(512)  */
#define CONV_SCALE  0.014731391274719742f   /* 1/sqrt(4608) */
#define CS2         (1.0f/4608.0f)

static __device__ __forceinline__ unsigned short f2bf(float x) {
    union { float f; unsigned int u; } a; a.f = x;
    unsigned int r = a.u + 0x7fffu + ((a.u >> 16) & 1u);    // round-nearest-even
    return (unsigned short)(r >> 16);
}

static __device__ __forceinline__ void gl_lds16(const void* g, void* l) {
    __builtin_amdgcn_global_load_lds(
        (const __attribute__((address_space(1))) unsigned int*)g,
        (__attribute__((address_space(3))) unsigned int*)l, 16, 0, 0);
}

// ---------------- kernel 1: style linear  s[16,512], split-K x4 -----------
__global__ void k_style(const float* __restrict__ w, const float* __restrict__ sw,
                        const float* __restrict__ sb, float* __restrict__ s) {
    int b = blockIdx.y, j0 = blockIdx.x * 64, t = threadIdx.x;
    __shared__ float wl[512];
    __shared__ float part[256];
    wl[t] = w[b*512 + t]; wl[t+256] = w[b*512 + t + 256];
    __syncthreads();
    int jl = t & 63, seg = t >> 6;
    const float4* row = (const float4*)(sw + (size_t)(j0 + jl)*512) + seg*32;
    const float*  wv  = wl + seg*128;
    float acc = 0.f;
#pragma unroll 4
    for (int k = 0; k < 32; ++k) {
        float4 v = row[k];
        acc += v.x*wv[4*k] + v.y*wv[4*k+1] + v.z*wv[4*k+2] + v.w*wv[4*k+3];
    }
    part[t] = acc;
    __syncthreads();
    if (t < 64)
        s[b*512 + j0 + t] = (part[t] + part[t+64] + part[t+128] + part[t+192])
                            * STYLE_SCALE + sb[j0 + t];
}

// ------- kernel 2: fused csq + weight pack (one cw row per block) ---------
__global__ void k_wprep(const float* __restrict__ cw, float* __restrict__ csq,
                        unsigned short* __restrict__ cwt) {
    int o = blockIdx.x, t = threadIdx.x;
    __shared__ float row[4608];
    const float4* src = (const float4*)(cw + (size_t)o*4608);
    for (int i = t; i < 1152; i += 256) ((float4*)row)[i] = src[i];
    __syncthreads();
    // csq
#pragma unroll
    for (int it = 0; it < 2; ++it) {
        int i = t + it*256;
        float a = 0.f;
#pragma unroll
        for (int k = 0; k < 9; ++k) { float v = row[i*9 + k]; a += v*v; }
        csq[(size_t)o*512 + i] = a * CS2;
    }
    // cwt pack: p = ic*36 + tap*4 + g
    for (int p = t; p < 576; p += 256) {
        int ic = p / 36, rem = p % 36;
        int tap = rem >> 2, g = rem & 3;
        int i0 = ic*32 + g*8;
        union { unsigned short us[8]; uint4 q; } u;
#pragma unroll
        for (int j = 0; j < 8; ++j)
            u.us[j] = f2bf(row[(i0 + j)*9 + tap] * CONV_SCALE);
        *(uint4*)(cwt + ((size_t)p*512 + o)*8) = u.q;
    }
}

// ---------------- kernel 3: sigma[b,o], split-K x4 ------------------------
__global__ void k_sigma(const float* __restrict__ s, const float* __restrict__ csq,
                        float* __restrict__ sig) {
    int b = blockIdx.y, o0 = blockIdx.x * 64, t = threadIdx.x;
    __shared__ float s2l[512];
    __shared__ float part[256];
    float v0 = s[b*512 + t], v1 = s[b*512 + t + 256];
    s2l[t] = v0*v0; s2l[t+256] = v1*v1;
    __syncthreads();
    int ol = t & 63, seg = t >> 6;
    const float4* row = (const float4*)(csq + (size_t)(o0 + ol)*512) + seg*32;
    const float*  sv  = s2l + seg*128;
    float acc = 0.f;
#pragma unroll 4
    for (int k = 0; k < 32; ++k) {
        float4 c = row[k];
        acc += c.x*sv[4*k] + c.y*sv[4*k+1] + c.z*sv[4*k+2] + c.w*sv[4*k+3];
    }
    part[t] = acc;
    __syncthreads();
    if (t < 64)
        sig[b*512 + o0 + t] = 1.0f / sqrtf(part[t] + part[t+64] + part[t+128]
                                           + part[t+192] + 1e-6f);
}

// ------- kernel 4: x' transpose+modulate -> xt[b][h*64+w][c] bf16 ---------
// float4 global loads, fp32 LDS tile (2-way-free banks), uint4 bf16 stores
__global__ void k_xt(const float* __restrict__ x, const float* __restrict__ s,
                     unsigned short* __restrict__ xt) {
    int h = blockIdx.x, b = blockIdx.y, t = threadIdx.x;
    __shared__ float tile[64][65];
    __shared__ float sl[64];
    for (int c0 = 0; c0 < 512; c0 += 64) {
        if (t < 64) sl[t] = s[b*512 + c0 + t];
#pragma unroll
        for (int it = 0; it < 4; ++it) {
            int idx = t + it*256;            // [c(64)][w4(16)]
            int c = idx >> 4, w4 = (idx & 15) * 4;
            float4 v = *(const float4*)(x + ((size_t)(b*512 + c0 + c)*4096) + h*64 + w4);
            tile[c][w4]   = v.x; tile[c][w4+1] = v.y;
            tile[c][w4+2] = v.z; tile[c][w4+3] = v.w;
        }
        __syncthreads();
#pragma unroll
        for (int it = 0; it < 2; ++it) {
            int idx = t + it*256;            // [wq(64)][g(8)]
            int wq = idx >> 3, c = (idx & 7) * 8;
            union { unsigned short us[8]; uint4 q; } u;
#pragma unroll
            for (int j = 0; j < 8; ++j)
                u.us[j] = f2bf(tile[c + j][wq] * sl[c + j]);
            *(uint4*)(xt + ((size_t)(b*4096 + h*64 + wq)*512 + c0 + c)) = u.q;
        }
        __syncthreads();
    }
}

// ---------------- kernel 5: implicit-GEMM MFMA conv -----------------------
// block: 64 o x 512 px (8 rows), 4 waves; wave = 64 o x 64 px x 2 rows
// LDS: xs[10 rows][66 cols][32 ch] bf16 (ch-group XOR-swizzled by col&3)
//      wsm[9 tap][4 g][64 o][8 j] bf16
__global__ __launch_bounds__(256, 2)
void k_conv(const unsigned short* __restrict__ xt, const unsigned short* __restrict__ cwt,
            const float* __restrict__ sig, const float* __restrict__ nw,
            const float* __restrict__ bias, const float* __restrict__ noise,
            float* __restrict__ out) {
    __shared__ short xs_s[10*66*32];         // 42240 B
    __shared__ short wsm_s[9*4*64*8];        // 36864 B

    const int tid  = threadIdx.x;
    const int lane = tid & 63;
    const int wave = tid >> 6;
    const int quad = lane >> 4;
    const int l15  = lane & 15;

    const int b     = blockIdx.y;
    const int oblk  = blockIdx.x & 7;
    const int pxblk = blockIdx.x >> 3;
    const int o0 = oblk * 64, h0 = pxblk * 8;

    // zero xs once: halo cols + out-of-image rows stay 0 forever
    for (int i = tid; i < 10*66*32/2; i += 256) ((unsigned int*)xs_s)[i] = 0u;
    __syncthreads();

    f32x4 acc[2][4][4];
#pragma unroll
    for (int rr = 0; rr < 2; ++rr)
#pragma unroll
        for (int mt = 0; mt < 4; ++mt)
#pragma unroll
            for (int nt = 0; nt < 4; ++nt) acc[rr][mt][nt] = (f32x4){0.f,0.f,0.f,0.f};

    for (int ic = 0; ic < 16; ++ic) {
        // ---- stage: 36 weight chunks + 40 x-row chunks, global_load_lds x16B
        for (int q = wave; q < 76; q += 4) {
            if (q < 36) {
                const unsigned short* src = cwt + ((size_t)(ic*36 + q)*512 + o0 + lane)*8;
                gl_lds16(src, wsm_s + q*512);
            } else {
                int xq = q - 36;
                int r = xq >> 2, p0 = (xq & 3) << 4;
                int gr = h0 - 1 + r;
                if (gr >= 0 && gr < 64) {
                    int p  = p0 + (lane >> 2);                    // pixel (w coord)
                    int cg = (lane & 3) ^ ((lane >> 2) & 3);      // swizzled ch-group
                    const unsigned short* src =
                        xt + ((size_t)(b*4096 + gr*64 + p)*512 + ic*32 + cg*8);
                    gl_lds16(src, xs_s + (r*66 + 1 + p0)*32);
                }
            }
        }
        __syncthreads();

        // ---- compute: 9 taps x 2 rows x (A/B ds_read_b128 + 16 mfma)
#pragma unroll
        for (int tap = 0; tap < 9; ++tap) {
            const int dy = tap / 3, dx = tap % 3;
            short8 af[4];
            const short8* wp = (const short8*)wsm_s;
            const short8* xp = (const short8*)xs_s;
#pragma unroll
            for (int mt = 0; mt < 4; ++mt)
                af[mt] = wp[(tap*4 + quad)*64 + mt*16 + l15];
#pragma unroll
            for (int rr = 0; rr < 2; ++rr) {
                const int row = wave + rr*4 + dy;
                short8 bfr[4];
#pragma unroll
                for (int nt = 0; nt < 4; ++nt) {
                    int wc   = nt*16 + l15 + dx - 1;              // global col, -1..64
                    int col  = wc + 1;
                    int slot = quad ^ (wc & 3);
                    bfr[nt] = xp[(row*66 + col)*4 + slot];
                }
#pragma unroll
                for (int mt = 0; mt < 4; ++mt)
#pragma unroll
                    for (int nt = 0; nt < 4; ++nt)
                        acc[rr][mt][nt] = __builtin_amdgcn_mfma_f32_16x16x32_bf16(
                            af[mt], bfr[nt], acc[rr][mt][nt], 0, 0, 0);
            }
        }
        __syncthreads();
    }

    // ---- epilogue: sigma scale + noise + bias + leaky relu ----
    float nz[2][4];
#pragma unroll
    for (int rr = 0; rr < 2; ++rr) {
        int h = h0 + wave + rr*4;
#pragma unroll
        for (int nt = 0; nt < 4; ++nt) nz[rr][nt] = noise[b*4096 + h*64 + nt*16 + l15];
    }
#pragma unroll
    for (int mt = 0; mt < 4; ++mt) {
#pragma unroll
        for (int r = 0; r < 4; ++r) {
            int o = o0 + mt*16 + quad*4 + r;
            float sg  = sig[b*512 + o];
            float nwv = nw[o], bv = bias[o];
#pragma unroll
            for (int rr = 0; rr < 2; ++rr) {
                int h = h0 + wave + rr*4;
#pragma unroll
                for (int nt = 0; nt < 4; ++nt) {
                    float v = acc[rr][mt][nt][r] * sg + nwv * nz[rr][nt] + bv;
                    v = (v >= 0.f) ? v : 0.2f * v;
                    out[((size_t)(b*512 + o)*4096) + h*64 + nt*16 + l15] = v;
                }
            }
        }
    }
}

// ---------------------------------------------------------------------------
extern "C" void kernel_launch(void* const* d_in, const int* in_sizes, int n_in,
                              void* d_out, int out_size, void* d_ws, size_t ws_size,
                              hipStream_t stream) {
    const float* x     = (const float*)d_in[0];
    const float* w     = (const float*)d_in[1];
    const float* sw    = (const float*)d_in[2];
    const float* sb    = (const float*)d_in[3];
    const float* cw    = (const float*)d_in[4];
    const float* nw    = (const float*)d_in[5];
    const float* bias  = (const float*)d_in[6];
    const float* noise = (const float*)d_in[7];
    float* out = (float*)d_out;

    char* ws = (char*)d_ws;
    unsigned short* xt  = (unsigned short*)(ws + 0);          // 67,108,864 B
    unsigned short* cwt = (unsigned short*)(ws + 67108864);   //  4,718,592 B
    float* s   = (float*)(ws + 71827456);                     //     32,768 B
    float* sig = (float*)(ws + 71860224);                     //     32,768 B
    float* csq = (float*)(ws + 71892992);                     //  1,048,576 B

    k_wprep<<<512, 256, 0, stream>>>(cw, csq, cwt);
    k_style<<<dim3(8, 16), 256, 0, stream>>>(w, sw, sb, s);
    k_sigma<<<dim3(8, 16), 256, 0, stream>>>(s, csq, sig);
    k_xt   <<<dim3(64, 16), 256, 0, stream>>>(x, s, xt);
    k_conv <<<dim3(64, 16), 256, 0, stream>>>(xt, cwt, sig, nw, bias, noise, out);
}

// Round 3
// 489.114 us; speedup vs baseline: 1.1825x; 1.0055x over previous
//
#include <hip/hip_runtime.h>

// ---------------------------------------------------------------------------
// SynthesisLayer (StyleGAN2 modulated conv) on MI355X.
//   s[b,i]   = w[b,:] @ sw[i,:]^T * SS + sb[i]
//   csq[o,i] = CS^2 * sum_t cw[o,i,t]^2
//   sig[b,o] = rsqrt( sum_i s^2[b,i]*csq[o,i] + eps )
//   x'[b,h,w,i] = bf16( x[b,i,h,w] * s[b,i] )
//   cwt[ic,tap,g,o,j] = bf16( cw[o, ic*32+g*8+j, tap]*CS )
//   y = sig * conv(x', cwt) + nw*noise + bias; leaky 0.2
// ---------------------------------------------------------------------------

typedef __attribute__((ext_vector_type(8))) short short8;    // 8 x bf16
typedef __attribute__((ext_vector_type(4))) float f32x4;     // mfma acc

#define STYLE_SCALE 0.044194173824159216f   /* 1/sqrt(512)  */
#define CONV_SCALE  0.014731391274719742f   /* 1/sqrt(4608) */
#define CS2         (1.0f/4608.0f)

static __device__ __forceinline__ unsigned short f2bf(float x) {
    union { float f; unsigned int u; } a; a.f = x;
    unsigned int r = a.u + 0x7fffu + ((a.u >> 16) & 1u);    // round-nearest-even
    return (unsigned short)(r >> 16);
}

static __device__ __forceinline__ void gl_lds16(const void* g, void* l) {
    __builtin_amdgcn_global_load_lds(
        (const __attribute__((address_space(1))) unsigned int*)g,
        (__attribute__((address_space(3))) unsigned int*)l, 16, 0, 0);
}

// ---------------- kernel 1: style linear  s[16,512], split-K x4 -----------
__global__ void k_style(const float* __restrict__ w, const float* __restrict__ sw,
                        const float* __restrict__ sb, float* __restrict__ s) {
    int b = blockIdx.y, j0 = blockIdx.x * 64, t = threadIdx.x;
    __shared__ float wl[512];
    __shared__ float part[256];
    wl[t] = w[b*512 + t]; wl[t+256] = w[b*512 + t + 256];
    __syncthreads();
    int jl = t & 63, seg = t >> 6;
    const float4* row = (const float4*)(sw + (size_t)(j0 + jl)*512) + seg*32;
    const float*  wv  = wl + seg*128;
    float acc = 0.f;
#pragma unroll 4
    for (int k = 0; k < 32; ++k) {
        float4 v = row[k];
        acc += v.x*wv[4*k] + v.y*wv[4*k+1] + v.z*wv[4*k+2] + v.w*wv[4*k+3];
    }
    part[t] = acc;
    __syncthreads();
    if (t < 64)
        s[b*512 + j0 + t] = (part[t] + part[t+64] + part[t+128] + part[t+192])
                            * STYLE_SCALE + sb[j0 + t];
}

// ------- kernel 2: fused csq + weight pack (one cw row per block) ---------
__global__ void k_wprep(const float* __restrict__ cw, float* __restrict__ csq,
                        unsigned short* __restrict__ cwt) {
    int o = blockIdx.x, t = threadIdx.x;
    __shared__ float row[4608];
    const float4* src = (const float4*)(cw + (size_t)o*4608);
    for (int i = t; i < 1152; i += 256) ((float4*)row)[i] = src[i];
    __syncthreads();
    // csq
#pragma unroll
    for (int it = 0; it < 2; ++it) {
        int i = t + it*256;
        float a = 0.f;
#pragma unroll
        for (int k = 0; k < 9; ++k) { float v = row[i*9 + k]; a += v*v; }
        csq[(size_t)o*512 + i] = a * CS2;
    }
    // cwt pack: p = ic*36 + tap*4 + g
    for (int p = t; p < 576; p += 256) {
        int ic = p / 36, rem = p % 36;
        int tap = rem >> 2, g = rem & 3;
        int i0 = ic*32 + g*8;
        union { unsigned short us[8]; uint4 q; } u;
#pragma unroll
        for (int j = 0; j < 8; ++j)
            u.us[j] = f2bf(row[(i0 + j)*9 + tap] * CONV_SCALE);
        *(uint4*)(cwt + ((size_t)p*512 + o)*8) = u.q;
    }
}

// ---------------- kernel 3: sigma[b,o], split-K x4 ------------------------
__global__ void k_sigma(const float* __restrict__ s, const float* __restrict__ csq,
                        float* __restrict__ sig) {
    int b = blockIdx.y, o0 = blockIdx.x * 64, t = threadIdx.x;
    __shared__ float s2l[512];
    __shared__ float part[256];
    float v0 = s[b*512 + t], v1 = s[b*512 + t + 256];
    s2l[t] = v0*v0; s2l[t+256] = v1*v1;
    __syncthreads();
    int ol = t & 63, seg = t >> 6;
    const float4* row = (const float4*)(csq + (size_t)(o0 + ol)*512) + seg*32;
    const float*  sv  = s2l + seg*128;
    float acc = 0.f;
#pragma unroll 4
    for (int k = 0; k < 32; ++k) {
        float4 c = row[k];
        acc += c.x*sv[4*k] + c.y*sv[4*k+1] + c.z*sv[4*k+2] + c.w*sv[4*k+3];
    }
    part[t] = acc;
    __syncthreads();
    if (t < 64)
        sig[b*512 + o0 + t] = 1.0f / sqrtf(part[t] + part[t+64] + part[t+128]
                                           + part[t+192] + 1e-6f);
}

// ------- kernel 4: x' transpose+modulate -> xt[b][h*64+w][c] bf16 ---------
__global__ void k_xt(const float* __restrict__ x, const float* __restrict__ s,
                     unsigned short* __restrict__ xt) {
    int h = blockIdx.x, b = blockIdx.y, t = threadIdx.x;
    __shared__ float tile[64][65];
    __shared__ float sl[64];
    for (int c0 = 0; c0 < 512; c0 += 64) {
        if (t < 64) sl[t] = s[b*512 + c0 + t];
#pragma unroll
        for (int it = 0; it < 4; ++it) {
            int idx = t + it*256;            // [c(64)][w4(16)]
            int c = idx >> 4, w4 = (idx & 15) * 4;
            float4 v = *(const float4*)(x + ((size_t)(b*512 + c0 + c)*4096) + h*64 + w4);
            tile[c][w4]   = v.x; tile[c][w4+1] = v.y;
            tile[c][w4+2] = v.z; tile[c][w4+3] = v.w;
        }
        __syncthreads();
#pragma unroll
        for (int it = 0; it < 2; ++it) {
            int idx = t + it*256;            // [wq(64)][g(8)]
            int wq = idx >> 3, c = (idx & 7) * 8;
            union { unsigned short us[8]; uint4 q; } u;
#pragma unroll
            for (int j = 0; j < 8; ++j)
                u.us[j] = f2bf(tile[c + j][wq] * sl[c + j]);
            *(uint4*)(xt + ((size_t)(b*4096 + h*64 + wq)*512 + c0 + c)) = u.q;
        }
        __syncthreads();
    }
}

// ---------------- kernel 5: implicit-GEMM MFMA conv -----------------------
// block: 64 o x 512 px (8 rows), 4 waves; wave = 64 o x 64 px x 2 CONTIGUOUS
// rows {2w, 2w+1}. B-fragments for the 4 distinct xs rows {2w..2w+3} are
// held in 2 rolling register buffers across the dy loop: B reads 72->48/ic.
// LDS: xs[10 rows][66 cols][32 ch] bf16 (ch-group XOR-swizzled by col&3)
//      wsm[9 tap][4 g][64 o][8 j] bf16
__global__ __launch_bounds__(256, 2)
void k_conv(const unsigned short* __restrict__ xt, const unsigned short* __restrict__ cwt,
            const float* __restrict__ sig, const float* __restrict__ nw,
            const float* __restrict__ bias, const float* __restrict__ noise,
            float* __restrict__ out) {
    __shared__ short xs_s[10*66*32];         // 42240 B
    __shared__ short wsm_s[9*4*64*8];        // 36864 B

    const int tid  = threadIdx.x;
    const int lane = tid & 63;
    const int wave = tid >> 6;
    const int quad = lane >> 4;
    const int l15  = lane & 15;

    const int b     = blockIdx.y;
    const int oblk  = blockIdx.x & 7;
    const int pxblk = blockIdx.x >> 3;
    const int o0 = oblk * 64, h0 = pxblk * 8;

    // zero xs once: halo cols + out-of-image rows stay 0 forever
    for (int i = tid; i < 10*66*32/2; i += 256) ((unsigned int*)xs_s)[i] = 0u;
    __syncthreads();

    f32x4 acc[2][4][4];
#pragma unroll
    for (int rr = 0; rr < 2; ++rr)
#pragma unroll
        for (int mt = 0; mt < 4; ++mt)
#pragma unroll
            for (int nt = 0; nt < 4; ++nt) acc[rr][mt][nt] = (f32x4){0.f,0.f,0.f,0.f};

    const short8* wp = (const short8*)wsm_s;
    const short8* xp = (const short8*)xs_s;

    for (int ic = 0; ic < 16; ++ic) {
        // ---- stage: 36 weight chunks + 40 x-row chunks, global_load_lds x16B
        for (int q = wave; q < 76; q += 4) {
            if (q < 36) {
                const unsigned short* src = cwt + ((size_t)(ic*36 + q)*512 + o0 + lane)*8;
                gl_lds16(src, wsm_s + q*512);
            } else {
                int xq = q - 36;
                int r = xq >> 2, p0 = (xq & 3) << 4;
                int gr = h0 - 1 + r;
                if (gr >= 0 && gr < 64) {
                    int p  = p0 + (lane >> 2);                    // pixel (w coord)
                    int cg = (lane & 3) ^ ((lane >> 2) & 3);      // swizzled ch-group
                    const unsigned short* src =
                        xt + ((size_t)(b*4096 + gr*64 + p)*512 + ic*32 + cg*8);
                    gl_lds16(src, xs_s + (r*66 + 1 + p0)*32);
                }
            }
        }
        __syncthreads();

        // ---- compute: dx outer; 2 rolling B row-buffers across dy ----
#pragma unroll
        for (int dx = 0; dx < 3; ++dx) {
            const int col0 = l15 + dx;                       // wc+1 for nt=0
            const int slot = quad ^ ((l15 + dx - 1) & 3);    // same for all nt
            const short8* xbase = xp + slot;
            short8 bufA[4], bufB[4];

#define LOADB(buf, d) do {                                                  \
            int rbase = ((2*wave + (d))*66 + col0) * 4;                     \
            buf[0] = xbase[rbase];        buf[1] = xbase[rbase + 64];       \
            buf[2] = xbase[rbase + 128];  buf[3] = xbase[rbase + 192];      \
        } while (0)

#define TAPSTEP(dy, C0, C1) do {                                            \
            const int tap = (dy)*3 + dx;                                    \
            short8 af[4];                                                   \
            _Pragma("unroll")                                               \
            for (int mt = 0; mt < 4; ++mt)                                  \
                af[mt] = wp[(tap*4 + quad)*64 + mt*16 + l15];               \
            _Pragma("unroll")                                               \
            for (int mt = 0; mt < 4; ++mt) {                                \
                _Pragma("unroll")                                           \
                for (int nt = 0; nt < 4; ++nt) {                            \
                    acc[0][mt][nt] = __builtin_amdgcn_mfma_f32_16x16x32_bf16( \
                        af[mt], C0[nt], acc[0][mt][nt], 0, 0, 0);           \
                    acc[1][mt][nt] = __builtin_amdgcn_mfma_f32_16x16x32_bf16( \
                        af[mt], C1[nt], acc[1][mt][nt], 0, 0, 0);           \
                }                                                           \
            }                                                               \
        } while (0)

            LOADB(bufA, 0);               // xs row 2w   (rr0, dy0)
            LOADB(bufB, 1);               // xs row 2w+1 (rr1, dy0)
            TAPSTEP(0, bufA, bufB);
            LOADB(bufA, 2);               // xs row 2w+2
            TAPSTEP(1, bufB, bufA);
            LOADB(bufB, 3);               // xs row 2w+3
            TAPSTEP(2, bufA, bufB);
#undef LOADB
#undef TAPSTEP
        }
        __syncthreads();
    }

    // ---- epilogue: sigma scale + noise + bias + leaky relu ----
    float nz[2][4];
#pragma unroll
    for (int rr = 0; rr < 2; ++rr) {
        int h = h0 + 2*wave + rr;
#pragma unroll
        for (int nt = 0; nt < 4; ++nt) nz[rr][nt] = noise[b*4096 + h*64 + nt*16 + l15];
    }
#pragma unroll
    for (int mt = 0; mt < 4; ++mt) {
#pragma unroll
        for (int r = 0; r < 4; ++r) {
            int o = o0 + mt*16 + quad*4 + r;
            float sg  = sig[b*512 + o];
            float nwv = nw[o], bv = bias[o];
#pragma unroll
            for (int rr = 0; rr < 2; ++rr) {
                int h = h0 + 2*wave + rr;
#pragma unroll
                for (int nt = 0; nt < 4; ++nt) {
                    float v = acc[rr][mt][nt][r] * sg + nwv * nz[rr][nt] + bv;
                    v = (v >= 0.f) ? v : 0.2f * v;
                    out[((size_t)(b*512 + o)*4096) + h*64 + nt*16 + l15] = v;
                }
            }
        }
    }
}

// ---------------------------------------------------------------------------
extern "C" void kernel_launch(void* const* d_in, const int* in_sizes, int n_in,
                              void* d_out, int out_size, void* d_ws, size_t ws_size,
                              hipStream_t stream) {
    const float* x     = (const float*)d_in[0];
    const float* w     = (const float*)d_in[1];
    const float* sw    = (const float*)d_in[2];
    const float* sb    = (const float*)d_in[3];
    const float* cw    = (const float*)d_in[4];
    const float* nw    = (const float*)d_in[5];
    const float* bias  = (const float*)d_in[6];
    const float* noise = (const float*)d_in[7];
    float* out = (float*)d_out;

    char* ws = (char*)d_ws;
    unsigned short* xt  = (unsigned short*)(ws + 0);          // 67,108,864 B
    unsigned short* cwt = (unsigned short*)(ws + 67108864);   //  4,718,592 B
    float* s   = (float*)(ws + 71827456);                     //     32,768 B
    float* sig = (float*)(ws + 71860224);                     //     32,768 B
    float* csq = (float*)(ws + 71892992);                     //  1,048,576 B

    k_wprep<<<512, 256, 0, stream>>>(cw, csq, cwt);
    k_style<<<dim3(8, 16), 256, 0, stream>>>(w, sw, sb, s);
    k_sigma<<<dim3(8, 16), 256, 0, stream>>>(s, csq, sig);
    k_xt   <<<dim3(64, 16), 256, 0, stream>>>(x, s, xt);
    k_conv <<<dim3(64, 16), 256, 0, stream>>>(xt, cwt, sig, nw, bias, noise, out);
}